// Round 1
// baseline (703.715 us; speedup 1.0000x reference)
//
#include <hip/hip_runtime.h>

#define NN   100000
#define NE   1600000
#define DIM  128
#define NB1  ((NN + 255) / 256)   // 391 blocks for node-indexed scans

typedef short          s16x8 __attribute__((ext_vector_type(8)));
typedef unsigned short u16x8 __attribute__((ext_vector_type(8)));
typedef float          f32x4 __attribute__((ext_vector_type(4)));

__device__ __forceinline__ unsigned short f2b(float f) {
    unsigned u = __float_as_uint(f);
    unsigned r = ((u >> 16) & 1u) + 0x7FFFu;   // RNE
    return (unsigned short)((u + r) >> 16);
}
__device__ __forceinline__ float b2f(unsigned short h) {
    return __uint_as_float(((unsigned)h) << 16);
}

// ---- fp32 -> bf16 feature cast (x table) ----
__global__ void k_cast_x(const float* __restrict__ x, unsigned short* __restrict__ xb) {
    int i = blockIdx.x * blockDim.x + threadIdx.x;     // over NN*DIM/4
    const float4* xp = (const float4*)x;
    float4 v = xp[i];
    ushort4 o;
    o.x = f2b(v.x); o.y = f2b(v.y); o.z = f2b(v.z); o.w = f2b(v.w);
    ((ushort4*)xb)[i] = o;
}

// ---- degree count ----
__global__ void k_deg(const int* __restrict__ dst, int* __restrict__ deg) {
    int i = blockIdx.x * blockDim.x + threadIdx.x;
    if (i < NE) atomicAdd(&deg[dst[i]], 1);
}

// ---- per-block sums of deg ----
__global__ void k_bsum(const int* __restrict__ deg, int* __restrict__ bsum) {
    __shared__ int sh[256];
    int i = blockIdx.x * 256 + threadIdx.x;
    sh[threadIdx.x] = (i < NN) ? deg[i] : 0;
    __syncthreads();
    for (int off = 128; off > 0; off >>= 1) {
        if (threadIdx.x < off) sh[threadIdx.x] += sh[threadIdx.x + off];
        __syncthreads();
    }
    if (threadIdx.x == 0) bsum[blockIdx.x] = sh[0];
}

// ---- exclusive scan of block sums (NB1 <= 512), single block ----
__global__ void k_scanb(const int* __restrict__ bsum, int* __restrict__ ebsum) {
    __shared__ int sh[512];
    int t = threadIdx.x;
    int v = (t < NB1) ? bsum[t] : 0;
    sh[t] = v;
    __syncthreads();
    for (int off = 1; off < 512; off <<= 1) {
        int a = (t >= off) ? sh[t - off] : 0;
        __syncthreads();
        sh[t] += a;
        __syncthreads();
    }
    if (t < NB1) ebsum[t] = sh[t] - v;
}

// ---- row_start = global exclusive scan; also cursor copy + deg_inv ----
__global__ void k_rowstart(const int* __restrict__ deg, const int* __restrict__ ebsum,
                           int* __restrict__ row_start, int* __restrict__ cursor,
                           float* __restrict__ deg_inv) {
    __shared__ int sh[256];
    int t = threadIdx.x;
    int i = blockIdx.x * 256 + t;
    int v = (i < NN) ? deg[i] : 0;
    sh[t] = v;
    __syncthreads();
    for (int off = 1; off < 256; off <<= 1) {
        int a = (t >= off) ? sh[t - off] : 0;
        __syncthreads();
        sh[t] += a;
        __syncthreads();
    }
    int excl = sh[t] - v;
    if (i < NN) {
        int rs = ebsum[blockIdx.x] + excl;
        row_start[i] = rs;
        cursor[i]    = rs;
        deg_inv[i]   = (v > 0) ? 1.0f / (float)v : 0.0f;
    }
}

// ---- CSR fill: csr[pos] = src for each edge, bucketed by dst ----
__global__ void k_fill(const int* __restrict__ src, const int* __restrict__ dst,
                       int* cursor, int* __restrict__ csr) {
    int i = blockIdx.x * blockDim.x + threadIdx.x;
    if (i < NE) {
        int d = dst[i];
        int p = atomicAdd(&cursor[d], 1);
        csr[p] = src[i];
    }
}

// ---- weight cast: Wt[n][k] = bf16( k<128 ? Wl[k][n] : Wr[k-128][n] ), 3 layers ----
__global__ void k_castw(const float* __restrict__ W1l, const float* __restrict__ W1r,
                        const float* __restrict__ W2l, const float* __restrict__ W2r,
                        const float* __restrict__ W3l, const float* __restrict__ W3r,
                        unsigned short* __restrict__ Wt1, unsigned short* __restrict__ Wt2,
                        unsigned short* __restrict__ Wt3) {
    int i = blockIdx.x * blockDim.x + threadIdx.x;   // 3 * 128 * 256
    int L = i >> 15;
    int rem = i & 32767;
    int n = rem >> 8;
    int k = rem & 255;
    const float* Wl = (L == 0) ? W1l : (L == 1) ? W2l : W3l;
    const float* Wr = (L == 0) ? W1r : (L == 1) ? W2r : W3r;
    unsigned short* Wt = (L == 0) ? Wt1 : (L == 1) ? Wt2 : Wt3;
    float v = (k < 128) ? Wl[k * 128 + n] : Wr[(k - 128) * 128 + n];
    Wt[n * 256 + k] = f2b(v);
}

// ---- mean aggregation: one wave per node; 4 neighbor slots x 16 col-chunks ----
__global__ void k_gather(const unsigned short* __restrict__ feat,
                         const int* __restrict__ row_start, const int* __restrict__ deg,
                         const float* __restrict__ deg_inv, const int* __restrict__ csr,
                         unsigned short* __restrict__ mean) {
    int lane = threadIdx.x & 63;
    int wv   = threadIdx.x >> 6;
    int n    = blockIdx.x * 4 + wv;        // NN % 4 == 0, grid exact
    int q = lane >> 4, c = lane & 15;      // q: neighbor slot, c: 16B column chunk
    int base = row_start[n];
    int d    = deg[n];
    float acc[8];
#pragma unroll
    for (int t = 0; t < 8; t++) acc[t] = 0.0f;
    const u16x8* fp = (const u16x8*)feat;
    for (int j = q; j < d; j += 4) {
        int s = csr[base + j];
        u16x8 v = fp[s * 16 + c];          // 16B = 8 bf16 of row s
#pragma unroll
        for (int t = 0; t < 8; t++) acc[t] += b2f(v[t]);
    }
    // butterfly-reduce across the 4 neighbor slots (lanes ^16, ^32)
#pragma unroll
    for (int t = 0; t < 8; t++) {
        acc[t] += __shfl_xor(acc[t], 16, 64);
        acc[t] += __shfl_xor(acc[t], 32, 64);
    }
    if (q == 0) {
        float s = deg_inv[n];
        u16x8 o;
#pragma unroll
        for (int t = 0; t < 8; t++) o[t] = f2b(acc[t] * s);
        ((u16x8*)mean)[n * 16 + c] = o;
    }
}

// ---- fused linear: out = act( [mean|h] @ Wt^T + b ), MFMA 16x16x32 bf16 ----
// MODE 0: relu, bf16 output; MODE 1: no act, fp32 output
template <int MODE>
__global__ void k_lin(const unsigned short* __restrict__ meanb,
                      const unsigned short* __restrict__ hb,
                      const unsigned short* __restrict__ Wt,
                      const float* __restrict__ bias, void* __restrict__ out) {
    int lane = threadIdx.x & 63;
    int wv   = threadIdx.x >> 6;
    int tile = blockIdx.x * 4 + wv;
    if (tile >= NN / 16) return;
    int m0 = tile * 16;
    int q = lane >> 4, c = lane & 15;
    const s16x8* mp = (const s16x8*)meanb;
    const s16x8* hp = (const s16x8*)hb;
    const s16x8* wp = (const s16x8*)Wt;
    int row = m0 + c;                      // A: m = lane&15, k-chunk = (lane>>4)*8
    s16x8 A[8];
#pragma unroll
    for (int kt = 0; kt < 4; kt++) A[kt] = mp[row * 16 + kt * 4 + q];
#pragma unroll
    for (int kt = 0; kt < 4; kt++) A[4 + kt] = hp[row * 16 + kt * 4 + q];
#pragma unroll
    for (int nt = 0; nt < 8; nt++) {
        f32x4 acc = {0.f, 0.f, 0.f, 0.f};
        int n = nt * 16 + c;               // B: n = lane&15, k-chunk = (lane>>4)*8
#pragma unroll
        for (int kt = 0; kt < 8; kt++) {
            s16x8 B = wp[n * 32 + kt * 4 + q];
            acc = __builtin_amdgcn_mfma_f32_16x16x32_bf16(A[kt], B, acc, 0, 0, 0);
        }
        float bv = bias[n];
#pragma unroll
        for (int r = 0; r < 4; r++) {
            float v = acc[r] + bv;
            int orow = m0 + q * 4 + r;     // C/D: col=lane&15, row=(lane>>4)*4+reg
            if (MODE == 0) {
                if (v < 0.f) v = 0.f;
                ((unsigned short*)out)[orow * DIM + n] = f2b(v);
            } else {
                ((float*)out)[orow * DIM + n] = v;
            }
        }
    }
}

extern "C" void kernel_launch(void* const* d_in, const int* in_sizes, int n_in,
                              void* d_out, int out_size, void* d_ws, size_t ws_size,
                              hipStream_t stream) {
    const float* x   = (const float*)d_in[1];
    const int*   ei  = (const int*)d_in[2];
    const int*   src = ei;
    const int*   dst = ei + NE;
    const float* W1l = (const float*)d_in[3];
    const float* W1r = (const float*)d_in[4];
    const float* b1  = (const float*)d_in[5];
    const float* W2l = (const float*)d_in[6];
    const float* W2r = (const float*)d_in[7];
    const float* b2  = (const float*)d_in[8];
    const float* W3l = (const float*)d_in[9];
    const float* W3r = (const float*)d_in[10];
    const float* b3  = (const float*)d_in[11];

    // workspace carve (all 256B aligned); total ~85 MB
    char* w = (char*)d_ws;
    auto carve = [&](size_t bytes) {
        void* p = (void*)w;
        w += (bytes + 255) & ~(size_t)255;
        return p;
    };
    int*   deg       = (int*)carve(NN * 4);
    int*   row_start = (int*)carve(NN * 4);
    int*   cursor    = (int*)carve(NN * 4);
    float* deg_inv   = (float*)carve(NN * 4);
    int*   bsum      = (int*)carve(NB1 * 4);
    int*   ebsum     = (int*)carve(NB1 * 4);
    int*   csr       = (int*)carve((size_t)NE * 4);
    unsigned short* Wt1 = (unsigned short*)carve(128 * 256 * 2);
    unsigned short* Wt2 = (unsigned short*)carve(128 * 256 * 2);
    unsigned short* Wt3 = (unsigned short*)carve(128 * 256 * 2);
    unsigned short* xb    = (unsigned short*)carve((size_t)NN * DIM * 2);
    unsigned short* meanb = (unsigned short*)carve((size_t)NN * DIM * 2);
    unsigned short* h1b   = (unsigned short*)carve((size_t)NN * DIM * 2);
    unsigned short* h2b   = xb;   // x no longer needed after layer 2's A-load

    hipMemsetAsync(deg, 0, NN * 4, stream);

    k_cast_x<<<NN * DIM / 4 / 256, 256, 0, stream>>>(x, xb);
    k_deg<<<(NE + 255) / 256, 256, 0, stream>>>(dst, deg);
    k_bsum<<<NB1, 256, 0, stream>>>(deg, bsum);
    k_scanb<<<1, 512, 0, stream>>>(bsum, ebsum);
    k_rowstart<<<NB1, 256, 0, stream>>>(deg, ebsum, row_start, cursor, deg_inv);
    k_fill<<<(NE + 255) / 256, 256, 0, stream>>>(src, dst, cursor, csr);
    k_castw<<<3 * 128 * 256 / 256, 256, 0, stream>>>(W1l, W1r, W2l, W2r, W3l, W3r,
                                                     Wt1, Wt2, Wt3);

    const int GB = NN / 4;                  // gather blocks (4 waves = 4 nodes each)
    const int LB = (NN / 16 + 3) / 4;       // k_lin blocks (4 waves = 4 tiles each)

    // layer 1: mean over xb -> h1 = relu(lin)
    k_gather<<<GB, 256, 0, stream>>>(xb, row_start, deg, deg_inv, csr, meanb);
    k_lin<0><<<LB, 256, 0, stream>>>(meanb, xb, Wt1, b1, (void*)h1b);
    // layer 2: mean over h1 -> h2 = relu(lin)
    k_gather<<<GB, 256, 0, stream>>>(h1b, row_start, deg, deg_inv, csr, meanb);
    k_lin<0><<<LB, 256, 0, stream>>>(meanb, h1b, Wt2, b2, (void*)h2b);
    // layer 3: mean over h2 -> dx_dt (fp32, no activation)
    k_gather<<<GB, 256, 0, stream>>>(h2b, row_start, deg, deg_inv, csr, meanb);
    k_lin<1><<<LB, 256, 0, stream>>>(meanb, h2b, Wt3, b3, d_out);
}